// Round 1
// baseline (475.335 us; speedup 1.0000x reference)
//
#include <hip/hip_runtime.h>

// Problem constants (B,S,H fixed by the reference)
#define Bn 4
#define Sn 256
#define Hn 768
#define Pn 32896        // Sn*(Sn+1)/2
#define Mn 1024         // Bn*Sn
#define HQ 192          // Hn/4

typedef float v4f __attribute__((ext_vector_type(4)));

// ---------------- GEMM: g/v = X @ W^T (both halves), bias folded into g ----
// g[m,o] = sum_h X[m,h] * W[o*1536 + h]        + bias[o]
// v[m,o] = sum_h X[m,h] * W[o*1536 + 768 + h]
// BM=BN=32 -> grid 32x24 = 768 blocks (3 blocks/CU vs previous 192 blocks).
#define BM 32
#define BN 32
#define BK 32
#define LDP 4   // LDS pad (keeps 16B alignment, breaks pow2 stride)

__global__ __launch_bounds__(256) void gemm_gv_kernel(
    const float* __restrict__ X,     // (1024, 768)
    const float* __restrict__ W,     // (768, 1536)
    const float* __restrict__ bias,  // (768)
    float* __restrict__ g,           // (1024, 768)
    float* __restrict__ v)           // (1024, 768)
{
    __shared__ float Xt[BK][BM + LDP];    // [k][m]
    __shared__ float Wgt[BK][BN + LDP];   // [k][o]
    __shared__ float Wvt[BK][BN + LDP];   // [k][o]

    const int tid = threadIdx.x;
    const int m0 = blockIdx.x * BM;
    const int n0 = blockIdx.y * BN;
    const int tx = tid & 15;        // 0..15  (cols / o), 2 cols each
    const int ty = tid >> 4;        // 0..15  (rows / m), 2 rows each
    const int lr = tid >> 3;        // 0..31  load row
    const int lk = (tid & 7) << 2;  // 0..28  load k offset (float4)

    float accg[2][2] = {};
    float accv[2][2] = {};

    for (int k0 = 0; k0 < Hn; k0 += BK) {
        // one float4 per thread per buffer covers the 32x32 tile exactly
        const float4 xq = *(const float4*)(X + (size_t)(m0 + lr) * Hn + k0 + lk);
        Xt[lk + 0][lr] = xq.x; Xt[lk + 1][lr] = xq.y;
        Xt[lk + 2][lr] = xq.z; Xt[lk + 3][lr] = xq.w;
        const float4 gq = *(const float4*)(W + (size_t)(n0 + lr) * (2 * Hn) + k0 + lk);
        Wgt[lk + 0][lr] = gq.x; Wgt[lk + 1][lr] = gq.y;
        Wgt[lk + 2][lr] = gq.z; Wgt[lk + 3][lr] = gq.w;
        const float4 vq = *(const float4*)(W + (size_t)(n0 + lr) * (2 * Hn) + Hn + k0 + lk);
        Wvt[lk + 0][lr] = vq.x; Wvt[lk + 1][lr] = vq.y;
        Wvt[lk + 2][lr] = vq.z; Wvt[lk + 3][lr] = vq.w;
        __syncthreads();
#pragma unroll
        for (int k = 0; k < BK; ++k) {
            const float2 xv = *(const float2*)&Xt[k][ty * 2];
            const float2 wg = *(const float2*)&Wgt[k][tx * 2];
            const float2 wv = *(const float2*)&Wvt[k][tx * 2];
            const float xr[2]  = {xv.x, xv.y};
            const float wgr[2] = {wg.x, wg.y};
            const float wvr[2] = {wv.x, wv.y};
#pragma unroll
            for (int r = 0; r < 2; ++r)
#pragma unroll
                for (int c = 0; c < 2; ++c) {
                    accg[r][c] = fmaf(xr[r], wgr[c], accg[r][c]);
                    accv[r][c] = fmaf(xr[r], wvr[c], accv[r][c]);
                }
        }
        __syncthreads();
    }

    const int oc = n0 + tx * 2;
    const float2 b2 = *(const float2*)(bias + oc);
#pragma unroll
    for (int r = 0; r < 2; ++r) {
        const int m = m0 + ty * 2 + r;
        float2 go, vo;
        go.x = accg[r][0] + b2.x; go.y = accg[r][1] + b2.y;
        vo.x = accv[r][0];        vo.y = accv[r][1];
        *(float2*)(g + (size_t)m * Hn + oc) = go;
        *(float2*)(v + (size_t)m * Hn + oc) = vo;
    }
}

// ---------------- Expansion: out[b,p,h] = tanh(g[b,i,h] + v[b,j,h]) --------
// 2D-tiled over the (i,j) triangle: each block holds TI g-rows + TJ v-rows in
// registers and emits TIxTJ output rows. Read amplification drops from 2.0
// (per-p blocks) to 0.25, so the write stream owns the HBM pipe.
#define TI 8
#define TJ 8
#define NT 32           // Sn / TI
#define NTILES 528      // NT*(NT+1)/2 upper-triangular tiles

__device__ __forceinline__ float fast_tanh(float x) {
    // tanh(x) = (e^{2x}-1)/(e^{2x}+1); v_exp + v_rcp, rel err ~1e-6
    const float x2 = fminf(fmaxf(2.0f * x, -40.0f), 40.0f);
    const float e = __expf(x2);
    return (e - 1.0f) * __builtin_amdgcn_rcpf(e + 1.0f);
}

__global__ __launch_bounds__(192) void expand_kernel(
    const float* __restrict__ g,   // (4, 256, 768), bias already added
    const float* __restrict__ v,   // (4, 256, 768)
    float* __restrict__ out)       // (4, 32896, 768)
{
    const int b = blockIdx.y;
    const int tt = blockIdx.x;

    // decode tt -> (ti, tj), row-major upper triangle of 32x32 tiles
    int ti = 0;
    while ((ti + 1) * NT - (((ti + 1) * ti) >> 1) <= tt) ++ti;
    const int tj = tt - (ti * NT - ((ti * (ti - 1)) >> 1)) + ti;
    const int i0 = ti * TI;
    const int j0 = tj * TJ;
    const int hq = threadIdx.x;     // 0..191, one float4 column each

    const v4f* __restrict__ g4 = (const v4f*)g;
    const v4f* __restrict__ v4p = (const v4f*)v;
    v4f* __restrict__ o4 = (v4f*)out;

    // stage tile rows in registers: 8+8 float4 = 64 VGPR of data
    v4f gr[TI], vr[TJ];
#pragma unroll
    for (int d = 0; d < TI; ++d)
        gr[d] = g4[(size_t)(b * Sn + i0 + d) * HQ + hq];
#pragma unroll
    for (int d = 0; d < TJ; ++d)
        vr[d] = v4p[(size_t)(b * Sn + j0 + d) * HQ + hq];

    const size_t obase = (size_t)b * Pn;

#pragma unroll
    for (int di = 0; di < TI; ++di) {
        const int i = i0 + di;
        const int rowbase = i * Sn - ((i * (i - 1)) >> 1) - i;  // p = rowbase + j
#pragma unroll
        for (int dj = 0; dj < TJ; ++dj) {
            if (ti == tj && dj < di) continue;   // below diagonal (uniform branch)
            const int p = rowbase + j0 + dj;
            const v4f s = gr[di] + vr[dj];
            v4f r;
            r.x = fast_tanh(s.x);
            r.y = fast_tanh(s.y);
            r.z = fast_tanh(s.z);
            r.w = fast_tanh(s.w);
            // nontemporal: keep L2 for the g/v working set
            __builtin_nontemporal_store(r, &o4[(obase + p) * HQ + hq]);
        }
    }
}

extern "C" void kernel_launch(void* const* d_in, const int* in_sizes, int n_in,
                              void* d_out, int out_size, void* d_ws, size_t ws_size,
                              hipStream_t stream) {
    const float* X    = (const float*)d_in[0];  // (4,256,768) fp32
    const float* W    = (const float*)d_in[1];  // (768,1536) fp32
    const float* bias = (const float*)d_in[2];  // (768) fp32
    float* out = (float*)d_out;                 // (4,32896,768) fp32

    float* g = (float*)d_ws;                    // 1024*768 floats
    float* v = g + (size_t)Mn * Hn;             // 1024*768 floats (6.3 MB total)

    dim3 gg(Mn / BM, Hn / BN);                  // 32 x 24 = 768 blocks
    gemm_gv_kernel<<<gg, 256, 0, stream>>>(X, W, bias, g, v);

    dim3 ge(NTILES, Bn);                        // 528 x 4 = 2112 blocks
    expand_kernel<<<ge, 192, 0, stream>>>(g, v, out);
}

// Round 3
// 464.145 us; speedup vs baseline: 1.0241x; 1.0241x over previous
//
#include <hip/hip_runtime.h>

// Problem constants (B,S,H fixed by the reference)
#define Bn 4
#define Sn 256
#define Hn 768
#define Pn 32896        // Sn*(Sn+1)/2
#define Mn 1024         // Bn*Sn
#define HQ 192          // Hn/4

typedef float v4f __attribute__((ext_vector_type(4)));

// ---------------- GEMM: g/v = X @ W^T (both halves), bias folded into g ----
// g[m,o] = sum_h X[m,h] * W[o*1536 + h]        + bias[o]
// v[m,o] = sum_h X[m,h] * W[o*1536 + 768 + h]
// BM=64, BN=32 -> grid 16x24 = 384 blocks (1.5/CU; 64x64 gave only 192 and
// idled 64 CUs, 32x32 was LDS-pipe-bound at 8 FMA per 3 reads).
// Per thread: 4 rows x 2 cols for g AND v = 16 FMA per k vs 1 b128 + 2 b64
// LDS reads -> VALU-bound (32 VALU cyc vs ~16 LDS cyc per wave per k).
#define BM 64
#define BN 32
#define BK 32
#define LDP 4   // LDS pad (keeps 16B row alignment, breaks pow2 stride)

__global__ __launch_bounds__(256) void gemm_gv_kernel(
    const float* __restrict__ X,     // (1024, 768)
    const float* __restrict__ W,     // (768, 1536)
    const float* __restrict__ bias,  // (768)
    float* __restrict__ g,           // (1024, 768)
    float* __restrict__ v)           // (1024, 768)
{
    __shared__ float Xt[BK][BM + LDP];    // [k][m]  32x68
    __shared__ float Wgt[BK][BN + LDP];   // [k][o]  32x36
    __shared__ float Wvt[BK][BN + LDP];   // [k][o]  32x36

    const int tid = threadIdx.x;
    const int m0 = blockIdx.x * BM;
    const int n0 = blockIdx.y * BN;
    const int tx = tid & 15;        // 0..15 (cols / o), 2 cols each
    const int ty = tid >> 4;        // 0..15 (rows / m), 4 rows each
    const int lr = tid >> 3;        // 0..31 load row
    const int lk = (tid & 7) << 2;  // 0..28 load k offset (float4)

    float accg[4][2] = {};
    float accv[4][2] = {};

    for (int k0 = 0; k0 < Hn; k0 += BK) {
        // X tile: 64 rows x 32 k -> two float4 per thread
#pragma unroll
        for (int half = 0; half < 2; ++half) {
            const int r = lr + half * 32;
            const float4 xq = *(const float4*)(X + (size_t)(m0 + r) * Hn + k0 + lk);
            Xt[lk + 0][r] = xq.x; Xt[lk + 1][r] = xq.y;
            Xt[lk + 2][r] = xq.z; Xt[lk + 3][r] = xq.w;
        }
        // W tiles: 32 rows x 32 k -> one float4 per thread each
        const float4 gq = *(const float4*)(W + (size_t)(n0 + lr) * (2 * Hn) + k0 + lk);
        Wgt[lk + 0][lr] = gq.x; Wgt[lk + 1][lr] = gq.y;
        Wgt[lk + 2][lr] = gq.z; Wgt[lk + 3][lr] = gq.w;
        const float4 vq = *(const float4*)(W + (size_t)(n0 + lr) * (2 * Hn) + Hn + k0 + lk);
        Wvt[lk + 0][lr] = vq.x; Wvt[lk + 1][lr] = vq.y;
        Wvt[lk + 2][lr] = vq.z; Wvt[lk + 3][lr] = vq.w;
        __syncthreads();
#pragma unroll
        for (int k = 0; k < BK; ++k) {
            const float4 xv = *(const float4*)&Xt[k][ty * 4];   // broadcast within tx group
            const float2 wg = *(const float2*)&Wgt[k][tx * 2];  // 16 distinct b64 / wave
            const float2 wv = *(const float2*)&Wvt[k][tx * 2];
            const float xr[4]  = {xv.x, xv.y, xv.z, xv.w};
            const float wgr[2] = {wg.x, wg.y};
            const float wvr[2] = {wv.x, wv.y};
#pragma unroll
            for (int r = 0; r < 4; ++r)
#pragma unroll
                for (int c = 0; c < 2; ++c) {
                    accg[r][c] = fmaf(xr[r], wgr[c], accg[r][c]);
                    accv[r][c] = fmaf(xr[r], wvr[c], accv[r][c]);
                }
        }
        __syncthreads();
    }

    const int oc = n0 + tx * 2;
    const float2 b2 = *(const float2*)(bias + oc);
#pragma unroll
    for (int r = 0; r < 4; ++r) {
        const int m = m0 + ty * 4 + r;
        float2 go, vo;
        go.x = accg[r][0] + b2.x; go.y = accg[r][1] + b2.y;
        vo.x = accv[r][0];        vo.y = accv[r][1];
        *(float2*)(g + (size_t)m * Hn + oc) = go;
        *(float2*)(v + (size_t)m * Hn + oc) = vo;
    }
}

// ---------------- Expansion: out[b,p,h] = tanh(g[b,i,h] + v[b,j,h]) --------
// 2D register tiling over the (i,j) triangle. g/v (6.3 MB) is L2/L3-resident,
// so reads are nearly free either way; the kernel is bound by the 404 MB
// nontemporal write stream. Goal: keep stores dense and VALU cheap.
#define TI 8
#define TJ 8
#define NT 32           // Sn / TI
#define NTILES 528      // NT*(NT+1)/2 upper-triangular tiles

__device__ __forceinline__ float fast_tanh(float x) {
    // tanh(x) = 1 - 2/(e^{2x}+1). No clamp needed: e=+inf -> 1, e=0 -> -1.
    // 5 VALU (mul, exp, add, rcp, fma) vs 8 for the clamped (e-1)/(e+1) form.
    const float e = __expf(2.0f * x);
    return fmaf(-2.0f, __builtin_amdgcn_rcpf(e + 1.0f), 1.0f);
}

__global__ __launch_bounds__(192) void expand_kernel(
    const float* __restrict__ g,   // (4, 256, 768), bias already added
    const float* __restrict__ v,   // (4, 256, 768)
    float* __restrict__ out)       // (4, 32896, 768)
{
    const int b = blockIdx.y;
    const int tt = blockIdx.x;

    // decode tt -> (ti, tj), row-major upper triangle of 32x32 tiles
    int ti = 0;
    while ((ti + 1) * NT - (((ti + 1) * ti) >> 1) <= tt) ++ti;
    const int tj = tt - (ti * NT - ((ti * (ti - 1)) >> 1)) + ti;
    const int i0 = ti * TI;
    const int j0 = tj * TJ;
    const int hq = threadIdx.x;     // 0..191, one float4 column each

    const v4f* __restrict__ g4 = (const v4f*)g;
    const v4f* __restrict__ v4p = (const v4f*)v;
    v4f* __restrict__ o4 = (v4f*)out;

    // stage tile rows in registers: 8+8 float4 = 64 VGPR of data
    v4f gr[TI], vr[TJ];
#pragma unroll
    for (int d = 0; d < TI; ++d)
        gr[d] = g4[(size_t)(b * Sn + i0 + d) * HQ + hq];
#pragma unroll
    for (int d = 0; d < TJ; ++d)
        vr[d] = v4p[(size_t)(b * Sn + j0 + d) * HQ + hq];

    const size_t obase = (size_t)b * Pn;

#pragma unroll
    for (int di = 0; di < TI; ++di) {
        const int i = i0 + di;
        const int rowbase = i * Sn - ((i * (i - 1)) >> 1) - i;  // p = rowbase + j
#pragma unroll
        for (int dj = 0; dj < TJ; ++dj) {
            if (ti == tj && dj < di) continue;   // below diagonal (uniform branch)
            const int p = rowbase + j0 + dj;
            const v4f s = gr[di] + vr[dj];
            v4f r;
            r.x = fast_tanh(s.x);
            r.y = fast_tanh(s.y);
            r.z = fast_tanh(s.z);
            r.w = fast_tanh(s.w);
            // nontemporal: keep L2 for the g/v working set
            __builtin_nontemporal_store(r, &o4[(obase + p) * HQ + hq]);
        }
    }
}

extern "C" void kernel_launch(void* const* d_in, const int* in_sizes, int n_in,
                              void* d_out, int out_size, void* d_ws, size_t ws_size,
                              hipStream_t stream) {
    const float* X    = (const float*)d_in[0];  // (4,256,768) fp32
    const float* W    = (const float*)d_in[1];  // (768,1536) fp32
    const float* bias = (const float*)d_in[2];  // (768) fp32
    float* out = (float*)d_out;                 // (4,32896,768) fp32

    float* g = (float*)d_ws;                    // 1024*768 floats
    float* v = g + (size_t)Mn * Hn;             // 1024*768 floats (6.3 MB total)

    dim3 gg(Mn / BM, Hn / BN);                  // 16 x 24 = 384 blocks
    gemm_gv_kernel<<<gg, 256, 0, stream>>>(X, W, bias, g, v);

    dim3 ge(NTILES, Bn);                        // 528 x 4 = 2112 blocks
    expand_kernel<<<ge, 192, 0, stream>>>(g, v, out);
}